// Round 2
// baseline (2039.694 us; speedup 1.0000x reference)
//
#include <hip/hip_runtime.h>
#include <math.h>

#define B_ 2
#define N_ 2048
#define IN_DIM_ 256
#define DIM_ 256
#define H_ 8
#define DH_ 32
#define TOPK_ 4
#define EPS_ 1e-5f
#define TEMP_ 0.17677669529663687f  // 1/sqrt(32)

// ---------------- LayerNorm: one row (256 floats) per 64-lane wave ----------------
__global__ __launch_bounds__(256) void ln_kernel(const float* __restrict__ x,
                                                 const float* __restrict__ gamma,
                                                 const float* __restrict__ beta,
                                                 float* __restrict__ xn) {
  int w = threadIdx.x >> 6, ld = threadIdx.x & 63;
  int row = blockIdx.x * 4 + w;
  const float4* xr = (const float4*)(x + (size_t)row * 256);
  float4 v = xr[ld];
  float s = v.x + v.y + v.z + v.w;
  float ss = v.x * v.x + v.y * v.y + v.z * v.z + v.w * v.w;
  #pragma unroll
  for (int off = 1; off < 64; off <<= 1) {
    s += __shfl_xor(s, off);
    ss += __shfl_xor(ss, off);
  }
  float mu = s * (1.0f / 256.0f);
  float var = ss * (1.0f / 256.0f) - mu * mu;
  float rstd = rsqrtf(var + EPS_);
  float4 g = ((const float4*)gamma)[ld];
  float4 bt = ((const float4*)beta)[ld];
  float4 o;
  o.x = (v.x - mu) * rstd * g.x + bt.x;
  o.y = (v.y - mu) * rstd * g.y + bt.y;
  o.z = (v.z - mu) * rstd * g.z + bt.z;
  o.w = (v.w - mu) * rstd * g.w + bt.w;
  ((float4*)(xn + (size_t)row * 256))[ld] = o;
}

// ---------------- fp32 tiled GEMM: C[m][n] = sum_k A[m*K+k] * Bm[n*K+k] ----------------
template <bool PROJ>
__global__ __launch_bounds__(256) void gemm_nt(const float* __restrict__ A,
                                               const float* __restrict__ Bm,
                                               float* __restrict__ C,
                                               const float* __restrict__ vres,
                                               const float* __restrict__ bias,
                                               int K, int ldc) {
  __shared__ float As[32][64];
  __shared__ float Bs[32][64];
  int m0 = blockIdx.x * 64, n0 = blockIdx.y * 64;
  int t = threadIdx.x;
  int tm = t & 15, tn = t >> 4;
  float acc[4][4] = {};
  for (int k0 = 0; k0 < K; k0 += 32) {
    __syncthreads();
    for (int f = t; f < 512; f += 256) {
      int row = f >> 3, j = f & 7;
      float4 a = *(const float4*)(A + (size_t)(m0 + row) * K + k0 + j * 4);
      As[j * 4 + 0][row] = a.x; As[j * 4 + 1][row] = a.y;
      As[j * 4 + 2][row] = a.z; As[j * 4 + 3][row] = a.w;
      float4 b = *(const float4*)(Bm + (size_t)(n0 + row) * K + k0 + j * 4);
      Bs[j * 4 + 0][row] = b.x; Bs[j * 4 + 1][row] = b.y;
      Bs[j * 4 + 2][row] = b.z; Bs[j * 4 + 3][row] = b.w;
    }
    __syncthreads();
    #pragma unroll
    for (int k = 0; k < 32; k++) {
      float4 a = *(const float4*)&As[k][tm * 4];
      float4 b = *(const float4*)&Bs[k][tn * 4];
      float av[4] = {a.x, a.y, a.z, a.w};
      float bv[4] = {b.x, b.y, b.z, b.w};
      #pragma unroll
      for (int i = 0; i < 4; i++)
        #pragma unroll
        for (int j = 0; j < 4; j++)
          acc[i][j] = fmaf(av[i], bv[j], acc[i][j]);
    }
  }
  #pragma unroll
  for (int i = 0; i < 4; i++) {
    int m = m0 + tm * 4 + i;
    int n = n0 + tn * 4;
    float4 r = {acc[i][0], acc[i][1], acc[i][2], acc[i][3]};
    if (PROJ) {
      float4 vr = *(const float4*)(vres + (size_t)m * 768 + n);
      float4 bb = *(const float4*)(bias + n);
      r.x += vr.x + bb.x; r.y += vr.y + bb.y;
      r.z += vr.z + bb.z; r.w += vr.w + bb.w;
    }
    *(float4*)(C + (size_t)m * ldc + n) = r;
  }
}

// ---------------- Flash attention + top-4, per-lane column ownership ----------------
// Grid: (N/32, H, B) = 1024 blocks. Block 256 threads.
// Thread t: qr=t>>3 (query row in tile of 32), qc=t&7 (owns s-columns qc*8..qc*8+7
// of each 64-tile). Each lane keeps PRIVATE online-softmax state (m,l,top4) and a
// full 32-dim O accumulator; one 8-lane butterfly merge at the end. No Ps LDS.
__global__ __launch_bounds__(256) void attn_kernel(const float* __restrict__ qkv,
                                                   float* __restrict__ msg,
                                                   float* __restrict__ out_s,
                                                   float* __restrict__ out_i) {
  const int l0 = blockIdx.x * 32;
  const int h = blockIdx.y;
  const int b = blockIdx.z;
  const int t = threadIdx.x;
  const int qr = t >> 3, qc = t & 7;

  // chunk c of row ss stored at column (c + (ss>>3)) & 7 -> for fixed c the 8 qc
  // lanes (ss = qc*8+j) hit 8 distinct bank-quads: conflict-free reads.
  __shared__ float4 Ks[64][8];
  __shared__ float4 Vs[64][8];

  const size_t rs = 768;  // qkv row stride
  const float* qrow = qkv + ((size_t)(b * N_) + l0 + qr) * rs + h * DH_;
  float4 qreg[8];
  #pragma unroll
  for (int c = 0; c < 8; c++) {
    float4 v = ((const float4*)qrow)[c];
    v.x *= TEMP_; v.y *= TEMP_; v.z *= TEMP_; v.w *= TEMP_;
    qreg[c] = v;
  }
  float4 o[8];
  #pragma unroll
  for (int c = 0; c < 8; c++) o[c] = make_float4(0.f, 0.f, 0.f, 0.f);
  float m = -INFINITY, l = 0.f;
  float tv[TOPK_];
  int ti[TOPK_];
  #pragma unroll
  for (int i = 0; i < TOPK_; i++) { tv[i] = -INFINITY; ti[i] = 0x7fffffff; }

  const float* kbase = qkv + (size_t)(b * N_) * rs + 256 + h * DH_;

  for (int s0 = 0; s0 < N_; s0 += 64) {
    __syncthreads();
    #pragma unroll
    for (int f0 = 0; f0 < 512; f0 += 256) {
      int f = f0 + t;
      int row = f >> 3, j = f & 7;
      int col = (j + (row >> 3)) & 7;
      const float* kp = kbase + (size_t)(s0 + row) * rs + j * 4;
      Ks[row][col] = *(const float4*)kp;
      Vs[row][col] = *(const float4*)(kp + 256);
    }
    __syncthreads();

    float pj[8];
    float tmax = -INFINITY;
    #pragma unroll
    for (int j = 0; j < 8; j++) {
      int ss = qc * 8 + j;
      float4 a = {0, 0, 0, 0};
      #pragma unroll
      for (int c = 0; c < 8; c++) {
        float4 kv = Ks[ss][(c + qc) & 7];  // chunk c of row ss
        float4 qv = qreg[c];
        a.x = fmaf(qv.x, kv.x, a.x);
        a.y = fmaf(qv.y, kv.y, a.y);
        a.z = fmaf(qv.z, kv.z, a.z);
        a.w = fmaf(qv.w, kv.w, a.w);
      }
      float sval = (a.x + a.y) + (a.z + a.w);
      pj[j] = sval;
      tmax = fmaxf(tmax, sval);
      int idx = s0 + ss;
      if (sval > tv[3] || (sval == tv[3] && idx < ti[3])) {
        int pos = 3;
        while (pos > 0 && (sval > tv[pos - 1] ||
                           (sval == tv[pos - 1] && idx < ti[pos - 1]))) {
          tv[pos] = tv[pos - 1];
          ti[pos] = ti[pos - 1];
          pos--;
        }
        tv[pos] = sval;
        ti[pos] = idx;
      }
    }
    if (tmax > m) {  // per-lane rescale (skipped when max unchanged)
      float alpha = __expf(m - tmax);
      #pragma unroll
      for (int c = 0; c < 8; c++) {
        o[c].x *= alpha; o[c].y *= alpha; o[c].z *= alpha; o[c].w *= alpha;
      }
      l *= alpha;
      m = tmax;
    }
    #pragma unroll
    for (int j = 0; j < 8; j++) {
      float p = __expf(pj[j] - m);
      l += p;
      int ss = qc * 8 + j;
      #pragma unroll
      for (int c = 0; c < 8; c++) {
        float4 vv = Vs[ss][(c + qc) & 7];
        o[c].x = fmaf(p, vv.x, o[c].x);
        o[c].y = fmaf(p, vv.y, o[c].y);
        o[c].z = fmaf(p, vv.z, o[c].z);
        o[c].w = fmaf(p, vv.w, o[c].w);
      }
    }
  }

  // ---- merge the 8 lanes of this query row (lanes are contiguous: xor 1,2,4) ----
  float mrow = m;
  mrow = fmaxf(mrow, __shfl_xor(mrow, 1));
  mrow = fmaxf(mrow, __shfl_xor(mrow, 2));
  mrow = fmaxf(mrow, __shfl_xor(mrow, 4));
  float scale = __expf(m - mrow);
  float lrow = l * scale;
  lrow += __shfl_xor(lrow, 1);
  lrow += __shfl_xor(lrow, 2);
  lrow += __shfl_xor(lrow, 4);
  #pragma unroll
  for (int c = 0; c < 8; c++) {
    o[c].x *= scale; o[c].y *= scale; o[c].z *= scale; o[c].w *= scale;
    #pragma unroll
    for (int d = 1; d <= 4; d <<= 1) {
      o[c].x += __shfl_xor(o[c].x, d);
      o[c].y += __shfl_xor(o[c].y, d);
      o[c].z += __shfl_xor(o[c].z, d);
      o[c].w += __shfl_xor(o[c].w, d);
    }
  }
  // top-4 butterfly merge (both lists sorted desc, ties -> lower index)
  #pragma unroll
  for (int d = 1; d <= 4; d <<= 1) {
    float ov[4];
    int oi[4];
    #pragma unroll
    for (int r = 0; r < 4; r++) {
      ov[r] = __shfl_xor(tv[r], d);
      oi[r] = __shfl_xor(ti[r], d);
    }
    #pragma unroll
    for (int r = 0; r < 4; r++) {
      float sval = ov[r];
      int idx = oi[r];
      if (sval > tv[3] || (sval == tv[3] && idx < ti[3])) {
        int pos = 3;
        while (pos > 0 && (sval > tv[pos - 1] ||
                           (sval == tv[pos - 1] && idx < ti[pos - 1]))) {
          tv[pos] = tv[pos - 1];
          ti[pos] = ti[pos - 1];
          pos--;
        }
        tv[pos] = sval;
        ti[pos] = idx;
      }
    }
  }

  float linv = 1.0f / lrow;
  // select this lane's output chunk (dims qc*4..qc*4+3)
  float4 oc = o[0];
  if (qc == 1) oc = o[1];
  if (qc == 2) oc = o[2];
  if (qc == 3) oc = o[3];
  if (qc == 4) oc = o[4];
  if (qc == 5) oc = o[5];
  if (qc == 6) oc = o[6];
  if (qc == 7) oc = o[7];
  oc.x *= linv; oc.y *= linv; oc.z *= linv; oc.w *= linv;

  float sc[4];
  #pragma unroll
  for (int r = 0; r < 4; r++) {
    sc[r] = __expf(tv[r] - mrow) * linv;
    const float* vp = qkv + ((size_t)(b * N_) + ti[r]) * rs + 512 + h * DH_ + qc * 4;
    float4 vv = *(const float4*)vp;
    oc.x = fmaf(-sc[r], vv.x, oc.x);
    oc.y = fmaf(-sc[r], vv.y, oc.y);
    oc.z = fmaf(-sc[r], vv.z, oc.z);
    oc.w = fmaf(-sc[r], vv.w, oc.w);
  }

  float* mp = msg + ((size_t)(b * N_) + l0 + qr) * DIM_ + h * DH_ + qc * 4;
  *(float4*)mp = oc;

  if (qc == 0) {
    size_t base = ((size_t)(b * N_ + l0 + qr)) * TOPK_;
    #pragma unroll
    for (int r = 0; r < 4; r++) {
      out_s[(base + r) * H_ + h] = sc[r];
      out_i[(base + r) * H_ + h] = (float)ti[r];
    }
  }
}

extern "C" void kernel_launch(void* const* d_in, const int* in_sizes, int n_in,
                              void* d_out, int out_size, void* d_ws, size_t ws_size,
                              hipStream_t stream) {
  const float* points = (const float*)d_in[0];
  const float* norm_gamma = (const float*)d_in[1];
  const float* norm_beta = (const float*)d_in[2];
  const float* w_qkv = (const float*)d_in[3];
  const float* w_proj = (const float*)d_in[4];
  const float* b_proj = (const float*)d_in[5];

  float* out0 = (float*)d_out;                       // message_flat (4096*256)
  float* out1 = out0 + (size_t)4096 * 256;           // topk_score (4096*4*8)
  float* out2 = out1 + (size_t)4096 * 4 * 8;         // topk_idx as float

  float* xn = (float*)d_ws;                          // 4096*256
  float* qkv = xn + (size_t)4096 * 256;              // 4096*768
  float* msg = qkv + (size_t)4096 * 768;             // 4096*256

  ln_kernel<<<1024, 256, 0, stream>>>(points, norm_gamma, norm_beta, xn);
  gemm_nt<false><<<dim3(64, 12), 256, 0, stream>>>(xn, w_qkv, qkv, nullptr,
                                                   nullptr, 256, 768);
  attn_kernel<<<dim3(N_ / 32, H_, B_), 256, 0, stream>>>(qkv, msg, out1, out2);
  gemm_nt<true><<<dim3(64, 4), 256, 0, stream>>>(msg, w_proj, out0, qkv + 512,
                                                 b_proj, 256, 256);
}